// Round 7
// baseline (221.362 us; speedup 1.0000x reference)
//
#include <hip/hip_runtime.h>

typedef __bf16 bf16x8 __attribute__((ext_vector_type(8)));
typedef float  f32x4  __attribute__((ext_vector_type(4)));

#define ND   64
#define HD   128
#define NSEG 1024

__device__ __forceinline__ int lower_bound_i(const int* __restrict__ a, int n, int v) {
  int lo = 0, hi = n;
  while (lo < hi) { int m = (lo + hi) >> 1; if (a[m] < v) lo = m + 1; else hi = m; }
  return lo;
}

// K0: seg_start[s] = first row of segment s (xb sorted); seg_start[NSEG] = n.
__global__ __launch_bounds__(128) void k_bounds(const int* __restrict__ xb, int n,
                                                int* __restrict__ ss) {
  const int s = blockIdx.x * 128 + threadIdx.x;
  if (s <= NSEG) ss[s] = lower_bound_i(xb, n, s);
}

// K1: one block per segment, 4 waves, wave w owns tiles w, w+4, ...
// Staging: global_load_lds, 4 x 1KB coalesced instructions per 16-row tile
// (16 cache lines each — optimal TA), per-wave double buffer, depth-1
// prefetch, exact counted s_waitcnt vmcnt(4) (prefetch never drained).
// LDS granule swizzle c ^= (row&7) applied on the SOURCE address (linear
// dest, rule 21); ds_read_b128 with the same XOR -> bank-floor reads.
// W1 frags in VGPRs. NO atomics anywhere. Masked tail accumulate.
// A frag: lane=(l16 row, lgrp), k = h*32 + lgrp*8 + e. B frag: same k map.
// D frag: col = lane&15, row = 4*(lane>>4)+reg  (HW-verified R1-R6).
__global__ __launch_bounds__(256, 3) void k_phi(const float* __restrict__ x,
                                                const int* __restrict__ ss,
                                                const float* __restrict__ W1,
                                                const float* __restrict__ b1,
                                                float* __restrict__ sums) {
  __shared__ __align__(16) char ldsS[4][2][4096];   // [wave][buf][tile]
  __shared__ float ldsR[4 * HD];
  const int lane = threadIdx.x & 63;
  const int wave = threadIdx.x >> 6;
  const int l16  = lane & 15;
  const int lgrp = lane >> 4;
  const int s    = blockIdx.x;

  const int r0   = ss[s];
  const int rows = ss[s + 1] - r0;

  // W1 fragments straight into VGPRs (W1 is 32KB, L2-hot across 1024 blocks)
  bf16x8 bfrag[2][8];
  #pragma unroll
  for (int kt = 0; kt < 2; ++kt)
    #pragma unroll
    for (int ct = 0; ct < 8; ++ct) {
      bf16x8 f;
      #pragma unroll
      for (int e = 0; e < 8; ++e)
        f[e] = (__bf16)W1[(kt * 32 + lgrp * 8 + e) * HD + ct * 16 + l16];
      bfrag[kt][ct] = f;
    }
  float b1v[8];
  #pragma unroll
  for (int ct = 0; ct < 8; ++ct) b1v[ct] = b1[ct * 16 + l16];

  // STAGE instr j: lane covers LDS slot-row rs=j*4+(l>>4), granule l&15 (linear
  // dest). Source granule = (l&15) ^ (rs&7)  -> swizzled-in-LDS tile.
  int rs[4], go[4];
  #pragma unroll
  for (int j = 0; j < 4; ++j) {
    rs[j] = j * 4 + (lane >> 4);
    go[j] = ((lane & 15) ^ (rs[j] & 7)) << 4;
  }
  // ds_read offsets: frag half h, chunk b: slot-row l16, true granule
  // h*8+lgrp*2+b, stored at (granule ^ (l16&7)).
  int roff[2][2];
  #pragma unroll
  for (int h = 0; h < 2; ++h)
    #pragma unroll
    for (int b = 0; b < 2; ++b)
      roff[h][b] = l16 * 256 + (((h * 8 + lgrp * 2 + b) ^ (l16 & 7)) << 4);

  const char* xb0 = (const char*)x + (size_t)r0 * 256;
  const int tiles = (rows + 15) >> 4;

#define STAGE(T, B)                                                              \
  { _Pragma("unroll")                                                            \
    for (int j = 0; j < 4; ++j) {                                                \
      const int rr = min((T) * 16 + rs[j], rows - 1);                            \
      const char* _s = xb0 + (size_t)rr * 256 + go[j];                           \
      __builtin_amdgcn_global_load_lds(                                          \
          (const __attribute__((address_space(1))) void*)_s,                     \
          (__attribute__((address_space(3))) void*)(&ldsS[wave][(B)][j * 1024]), \
          16, 0, 0);                                                             \
    } }

  float seg_acc[8] = {0.f, 0.f, 0.f, 0.f, 0.f, 0.f, 0.f, 0.f};

  int t = wave;
  if (t < tiles) {
    STAGE(t, 0);
    int buf = 0;
    for (;;) {
      const int tn = t + 4;
      const int tp = min(tn, tiles - 1);
      STAGE(tp, buf ^ 1);                       // prefetch (dup at tail, unread)
      asm volatile("s_waitcnt vmcnt(4)" ::: "memory");   // current tile landed
      __builtin_amdgcn_sched_barrier(0);

      f32x4 q00 = *(const f32x4*)(&ldsS[wave][buf][roff[0][0]]);
      f32x4 q01 = *(const f32x4*)(&ldsS[wave][buf][roff[0][1]]);
      f32x4 q10 = *(const f32x4*)(&ldsS[wave][buf][roff[1][0]]);
      f32x4 q11 = *(const f32x4*)(&ldsS[wave][buf][roff[1][1]]);
      bf16x8 a0, a1;
      #pragma unroll
      for (int e = 0; e < 4; ++e) {
        a0[e] = (__bf16)q00[e]; a0[e + 4] = (__bf16)q01[e];
        a1[e] = (__bf16)q10[e]; a1[e + 4] = (__bf16)q11[e];
      }
      f32x4 acc[8];
      #pragma unroll
      for (int ct = 0; ct < 8; ++ct) {
        f32x4 c; c[0] = c[1] = c[2] = c[3] = b1v[ct];
        c = __builtin_amdgcn_mfma_f32_16x16x32_bf16(a0, bfrag[0][ct], c, 0, 0, 0);
        c = __builtin_amdgcn_mfma_f32_16x16x32_bf16(a1, bfrag[1][ct], c, 0, 0, 0);
        acc[ct] = c;
      }

      const int lim = rows - t * 16;            // >=16 except the last tile
      if (lim >= 16) {
        #pragma unroll
        for (int ct = 0; ct < 8; ++ct)
          seg_acc[ct] += (fmaxf(acc[ct][0], 0.f) + fmaxf(acc[ct][1], 0.f)) +
                         (fmaxf(acc[ct][2], 0.f) + fmaxf(acc[ct][3], 0.f));
      } else {
        #pragma unroll
        for (int ct = 0; ct < 8; ++ct)
          #pragma unroll
          for (int i = 0; i < 4; ++i)
            seg_acc[ct] += (4 * lgrp + i < lim) ? fmaxf(acc[ct][i], 0.f) : 0.f;
      }

      buf ^= 1; t = tn;
      if (t >= tiles) break;
    }
    // dangling prefetch writes must land before this wave can retire
    asm volatile("s_waitcnt vmcnt(0)" ::: "memory");
  }
#undef STAGE

  // cross-rowgroup then cross-wave reduce; single plain store (no atomics)
  #pragma unroll
  for (int ct = 0; ct < 8; ++ct) {
    float v = seg_acc[ct];
    v += __shfl_xor(v, 16);
    v += __shfl_xor(v, 32);
    if (lane < 16) ldsR[wave * HD + ct * 16 + l16] = v;
  }
  __syncthreads();
  if (threadIdx.x < HD) {
    const float r = ldsR[threadIdx.x] + ldsR[HD + threadIdx.x] +
                    ldsR[2 * HD + threadIdx.x] + ldsR[3 * HD + threadIdx.x];
    sums[s * HD + threadIdx.x] = r;
  }
}

// K2: per segment: mean -> @W2+b2 (deferred past the mean) -> relu(@W3+b3) -> @W4+b4
__global__ __launch_bounds__(128) void k_rho(const float* __restrict__ sums,
                                             const int* __restrict__ ss,
                                             const float* __restrict__ W2, const float* __restrict__ b2,
                                             const float* __restrict__ W3, const float* __restrict__ b3,
                                             const float* __restrict__ W4, const float* __restrict__ b4,
                                             float* __restrict__ out) {
  const int s = blockIdx.x;
  const int j = threadIdx.x;
  __shared__ float bufA[HD];
  __shared__ float bufB[HD];

  const float c = (float)(ss[s + 1] - ss[s]);
  const float inv = 1.f / fmaxf(c, 1.f);
  bufA[j] = sums[s * HD + j] * inv;
  __syncthreads();

  float hid = b2[j];
  #pragma unroll 4
  for (int k = 0; k < HD; ++k) hid = fmaf(bufA[k], W2[k * HD + j], hid);
  if (c == 0.f) hid = 0.f;                    // reference: empty segment -> hid = 0
  bufB[j] = hid;
  __syncthreads();

  float t = b3[j];
  #pragma unroll 4
  for (int k = 0; k < HD; ++k) t = fmaf(bufB[k], W3[k * HD + j], t);
  t = fmaxf(t, 0.f);
  bufA[j] = t;
  __syncthreads();

  if (j < 16) {
    float o = b4[j];
    #pragma unroll 4
    for (int k = 0; k < HD; ++k) o = fmaf(bufA[k], W4[k * 16 + j], o);
    out[s * 16 + j] = o;
  }
}

extern "C" void kernel_launch(void* const* d_in, const int* in_sizes, int n_in,
                              void* d_out, int out_size, void* d_ws, size_t ws_size,
                              hipStream_t stream) {
  const float* x  = (const float*)d_in[0];
  const int*   xb = (const int*)  d_in[1];
  const float* W1 = (const float*)d_in[2];
  const float* b1 = (const float*)d_in[3];
  const float* W2 = (const float*)d_in[4];
  const float* b2 = (const float*)d_in[5];
  const float* W3 = (const float*)d_in[6];
  const float* b3 = (const float*)d_in[7];
  const float* W4 = (const float*)d_in[8];
  const float* b4 = (const float*)d_in[9];
  float* out = (float*)d_out;
  const int n = in_sizes[1];

  float* sums = (float*)d_ws;                      // [NSEG][HD]
  int*   ss   = (int*)(sums + (size_t)NSEG * HD);  // [NSEG+1]

  k_bounds<<<(NSEG + 1 + 127) / 128, 128, 0, stream>>>(xb, n, ss);
  k_phi<<<NSEG, 256, 0, stream>>>(x, ss, W1, b1, sums);
  k_rho<<<NSEG, 128, 0, stream>>>(sums, ss, W2, b2, W3, b3, W4, b4, out);
}

// Round 8
// 144.659 us; speedup vs baseline: 1.5302x; 1.5302x over previous
//
#include <hip/hip_runtime.h>

typedef __bf16 bf16x8 __attribute__((ext_vector_type(8)));
typedef float  f32x4  __attribute__((ext_vector_type(4)));

#define ND   64
#define HD   128
#define NSEG 1024

__device__ __forceinline__ int lower_bound_i(const int* __restrict__ a, int n, int v) {
  int lo = 0, hi = n;
  while (lo < hi) { int m = (lo + hi) >> 1; if (a[m] < v) lo = m + 1; else hi = m; }
  return lo;
}

// K0: seg_start[s] = first row of segment s (xb sorted); seg_start[NSEG] = n.
__global__ __launch_bounds__(128) void k_bounds(const int* __restrict__ xb, int n,
                                                int* __restrict__ ss) {
  const int s = blockIdx.x * 128 + threadIdx.x;
  if (s <= NSEG) ss[s] = lower_bound_i(xb, n, s);
}

// K1: one block per segment, 4 waves, wave w owns tiles w, w+4, ...
// x path: 4 fully-contiguous 1KB global load instrs per 16-row tile (lane i ->
// +i*16B; minimal TA transactions), depth-1 register prefetch, then an
// in-wave LDS transit (4 ds_write_b128 + 4 ds_read_b128, granule-XOR swizzle
// g' = g ^ (row&7), 2-way banks = free) to rebuild MFMA A-fragments.
// NO atomics, NO gload_lds, NO manual waitcnt. W1 frags in LDS (R6-best).
// A frag: lane=(l16 row, lgrp), k = h*32 + lgrp*8 + e. B frag: same k map.
// D frag: col = lane&15, row = 4*(lane>>4)+reg  (HW-verified R1-R7).
__global__ __launch_bounds__(256, 4) void k_phi(const float* __restrict__ x,
                                                const int* __restrict__ ss,
                                                const float* __restrict__ W1,
                                                const float* __restrict__ b1,
                                                float* __restrict__ sums) {
  __shared__ __align__(16) char ldsW[16 * 1024];
  __shared__ __align__(16) char ldsX[4][4096];    // per-wave transit buffer
  __shared__ float ldsR[4 * HD];
  const int lane = threadIdx.x & 63;
  const int wave = threadIdx.x >> 6;
  const int l16  = lane & 15;
  const int lgrp = lane >> 4;
  const int s    = blockIdx.x;

  const int r0   = ss[s];
  const int rows = ss[s + 1] - r0;

  // stage W1 fragments into LDS: frag f = kt*8+ct at [f][lane][16B]
  #pragma unroll
  for (int i = 0; i < 4; ++i) {
    const int f = wave + i * 4, kt = f >> 3, ct = f & 7;
    bf16x8 fr;
    #pragma unroll
    for (int e = 0; e < 8; ++e)
      fr[e] = (__bf16)W1[(kt * 32 + lgrp * 8 + e) * HD + ct * 16 + l16];
    *(bf16x8*)(&ldsW[f * 1024 + lane * 16]) = fr;
  }
  float b1v[8];
  #pragma unroll
  for (int ct = 0; ct < 8; ++ct) b1v[ct] = b1[ct * 16 + l16];
  __syncthreads();

  // loop-invariant transit addresses ------------------------------------
  char* myX = &ldsX[wave][0];
  // write side: instr j covers local rows [4j,4j+4); lane holds row 4j+lgrp,
  // granule g = l16, stored at g ^ (row&7).
  int waddr[4];
  #pragma unroll
  for (int j = 0; j < 4; ++j) {
    const int rl = 4 * j + lgrp;
    waddr[j] = rl * 256 + ((l16 ^ (rl & 7)) << 4);
  }
  // read side: lane reads row l16; a0 = granules {2lgrp, 2lgrp+1} (k=8lgrp+e),
  // a1 = granules {8+2lgrp, 9+2lgrp} (k=32+8lgrp+e); each at g ^ (l16&7).
  const int sw  = l16 & 7;
  const int ra0 = l16 * 256 + (((2 * lgrp)     ^ sw) << 4);
  const int ra1 = l16 * 256 + (((2 * lgrp + 1) ^ sw) << 4);
  const int ra2 = l16 * 256 + (((8 + 2 * lgrp) ^ sw) << 4);
  const int ra3 = l16 * 256 + (((9 + 2 * lgrp) ^ sw) << 4);

  const float* xb0 = x + (size_t)r0 * ND;
  const int g4    = l16 * 4;            // float offset of this lane's granule
  const int tiles = (rows + 15) >> 4;

#define LOADC(T, R0, R1, R2, R3)                                        \
  {                                                                     \
    const int rb = (T) * 16 + lgrp;                                     \
    R0 = *(const f32x4*)(xb0 + (size_t)min(rb,      rows - 1) * ND + g4);\
    R1 = *(const f32x4*)(xb0 + (size_t)min(rb + 4,  rows - 1) * ND + g4);\
    R2 = *(const f32x4*)(xb0 + (size_t)min(rb + 8,  rows - 1) * ND + g4);\
    R3 = *(const f32x4*)(xb0 + (size_t)min(rb + 12, rows - 1) * ND + g4);\
  }

  float seg_acc[8] = {0.f, 0.f, 0.f, 0.f, 0.f, 0.f, 0.f, 0.f};

  int t = wave;
  if (t < tiles) {
    f32x4 v0, v1, v2, v3;
    LOADC(t, v0, v1, v2, v3);
    for (;;) {
      const int tn = t + 4;
      const int tp = min(tn, tiles - 1);
      f32x4 w0, w1, w2, w3;
      LOADC(tp, w0, w1, w2, w3);        // depth-1 prefetch (dup at tail, unread)

      // transit: regs -> LDS (swizzled) -> fragment-order regs
      *(f32x4*)(myX + waddr[0]) = v0;
      *(f32x4*)(myX + waddr[1]) = v1;
      *(f32x4*)(myX + waddr[2]) = v2;
      *(f32x4*)(myX + waddr[3]) = v3;
      f32x4 q00 = *(const f32x4*)(myX + ra0);
      f32x4 q01 = *(const f32x4*)(myX + ra1);
      f32x4 q10 = *(const f32x4*)(myX + ra2);
      f32x4 q11 = *(const f32x4*)(myX + ra3);

      bf16x8 a0, a1;
      #pragma unroll
      for (int e = 0; e < 4; ++e) {
        a0[e] = (__bf16)q00[e]; a0[e + 4] = (__bf16)q01[e];
        a1[e] = (__bf16)q10[e]; a1[e + 4] = (__bf16)q11[e];
      }
      int lb = lane * 16;
      asm volatile("" : "+v"(lb));      // defeat LICM: keep W1 frag reads in-loop
      f32x4 acc[8];
      #pragma unroll
      for (int ct = 0; ct < 8; ++ct) {
        f32x4 c; c[0] = c[1] = c[2] = c[3] = b1v[ct];
        bf16x8 f0 = *(const bf16x8*)(&ldsW[ct * 1024 + lb]);
        bf16x8 f1 = *(const bf16x8*)(&ldsW[(8 + ct) * 1024 + lb]);
        c = __builtin_amdgcn_mfma_f32_16x16x32_bf16(a0, f0, c, 0, 0, 0);
        c = __builtin_amdgcn_mfma_f32_16x16x32_bf16(a1, f1, c, 0, 0, 0);
        acc[ct] = c;
      }

      const int lim = rows - t * 16;    // >=16 except the last tile
      if (lim >= 16) {
        #pragma unroll
        for (int ct = 0; ct < 8; ++ct)
          seg_acc[ct] += (fmaxf(acc[ct][0], 0.f) + fmaxf(acc[ct][1], 0.f)) +
                         (fmaxf(acc[ct][2], 0.f) + fmaxf(acc[ct][3], 0.f));
      } else {
        #pragma unroll
        for (int ct = 0; ct < 8; ++ct)
          #pragma unroll
          for (int i = 0; i < 4; ++i)
            seg_acc[ct] += (4 * lgrp + i < lim) ? fmaxf(acc[ct][i], 0.f) : 0.f;
      }

      v0 = w0; v1 = w1; v2 = w2; v3 = w3;
      t = tn;
      if (t >= tiles) break;
    }
  }
#undef LOADC

  // cross-rowgroup then cross-wave reduce; single plain store (no atomics)
  #pragma unroll
  for (int ct = 0; ct < 8; ++ct) {
    float v = seg_acc[ct];
    v += __shfl_xor(v, 16);
    v += __shfl_xor(v, 32);
    if (lane < 16) ldsR[wave * HD + ct * 16 + l16] = v;
  }
  __syncthreads();
  if (threadIdx.x < HD) {
    const float r = ldsR[threadIdx.x] + ldsR[HD + threadIdx.x] +
                    ldsR[2 * HD + threadIdx.x] + ldsR[3 * HD + threadIdx.x];
    sums[s * HD + threadIdx.x] = r;
  }
}

// K2: per segment: mean -> @W2+b2 (deferred past the mean) -> relu(@W3+b3) -> @W4+b4
__global__ __launch_bounds__(128) void k_rho(const float* __restrict__ sums,
                                             const int* __restrict__ ss,
                                             const float* __restrict__ W2, const float* __restrict__ b2,
                                             const float* __restrict__ W3, const float* __restrict__ b3,
                                             const float* __restrict__ W4, const float* __restrict__ b4,
                                             float* __restrict__ out) {
  const int s = blockIdx.x;
  const int j = threadIdx.x;
  __shared__ float bufA[HD];
  __shared__ float bufB[HD];

  const float c = (float)(ss[s + 1] - ss[s]);
  const float inv = 1.f / fmaxf(c, 1.f);
  bufA[j] = sums[s * HD + j] * inv;
  __syncthreads();

  float hid = b2[j];
  #pragma unroll 4
  for (int k = 0; k < HD; ++k) hid = fmaf(bufA[k], W2[k * HD + j], hid);
  if (c == 0.f) hid = 0.f;                    // reference: empty segment -> hid = 0
  bufB[j] = hid;
  __syncthreads();

  float t = b3[j];
  #pragma unroll 4
  for (int k = 0; k < HD; ++k) t = fmaf(bufB[k], W3[k * HD + j], t);
  t = fmaxf(t, 0.f);
  bufA[j] = t;
  __syncthreads();

  if (j < 16) {
    float o = b4[j];
    #pragma unroll 4
    for (int k = 0; k < HD; ++k) o = fmaf(bufA[k], W4[k * 16 + j], o);
    out[s * 16 + j] = o;
  }
}

extern "C" void kernel_launch(void* const* d_in, const int* in_sizes, int n_in,
                              void* d_out, int out_size, void* d_ws, size_t ws_size,
                              hipStream_t stream) {
  const float* x  = (const float*)d_in[0];
  const int*   xb = (const int*)  d_in[1];
  const float* W1 = (const float*)d_in[2];
  const float* b1 = (const float*)d_in[3];
  const float* W2 = (const float*)d_in[4];
  const float* b2 = (const float*)d_in[5];
  const float* W3 = (const float*)d_in[6];
  const float* b3 = (const float*)d_in[7];
  const float* W4 = (const float*)d_in[8];
  const float* b4 = (const float*)d_in[9];
  float* out = (float*)d_out;
  const int n = in_sizes[1];

  float* sums = (float*)d_ws;                      // [NSEG][HD]
  int*   ss   = (int*)(sums + (size_t)NSEG * HD);  // [NSEG+1]

  k_bounds<<<(NSEG + 1 + 127) / 128, 128, 0, stream>>>(xb, n, ss);
  k_phi<<<NSEG, 256, 0, stream>>>(x, ss, W1, b1, sums);
  k_rho<<<NSEG, 128, 0, stream>>>(sums, ss, W2, b2, W3, b3, W4, b4, out);
}

// Round 9
// 141.278 us; speedup vs baseline: 1.5669x; 1.0239x over previous
//
#include <hip/hip_runtime.h>

typedef __bf16 bf16x8 __attribute__((ext_vector_type(8)));
typedef float  f32x4  __attribute__((ext_vector_type(4)));

#define ND   64
#define HD   128
#define NSEG 1024

__device__ __forceinline__ int lower_bound_i(const int* __restrict__ a, int n, int v) {
  int lo = 0, hi = n;
  while (lo < hi) { int m = (lo + hi) >> 1; if (a[m] < v) lo = m + 1; else hi = m; }
  return lo;
}

// K0: seg_start[s] = first row of segment s (xb sorted); seg_start[NSEG] = n.
__global__ __launch_bounds__(128) void k_bounds(const int* __restrict__ xb, int n,
                                                int* __restrict__ ss) {
  const int s = blockIdx.x * 128 + threadIdx.x;
  if (s <= NSEG) ss[s] = lower_bound_i(xb, n, s);
}

// K1: one block per segment, EIGHT waves (512 thr) -> 32 waves/CU for read TLP.
// Lean-register design (~55 VGPR, launch_bounds(512,8) = 64-reg budget):
//  - ct-serialized MFMA accumulation (one f32x4 acc live at a time)
//  - W1 frags + b1 read from LDS every tile (LICM defeated)
//  - no explicit prefetch: 8 waves/SIMD TLP hides HBM latency
// NO atomics, NO gload_lds, NO manual waitcnt.
// A frag: lane=(l16 row, lgrp), k = h*32 + lgrp*8 + e. B frag: same k map.
// D frag: col = lane&15, row = 4*(lane>>4)+reg  (HW-verified R1-R8).
__global__ __launch_bounds__(512, 8) void k_phi(const float* __restrict__ x,
                                                const int* __restrict__ ss,
                                                const float* __restrict__ W1,
                                                const float* __restrict__ b1,
                                                float* __restrict__ sums) {
  __shared__ __align__(16) char ldsW[16 * 1024];
  __shared__ float ldsB[HD];
  __shared__ float ldsR[8 * HD];
  const int lane = threadIdx.x & 63;
  const int wave = threadIdx.x >> 6;          // 0..7
  const int l16  = lane & 15;
  const int lgrp = lane >> 4;
  const int s    = blockIdx.x;

  const int r0   = ss[s];
  const int rows = ss[s + 1] - r0;

  // stage W1 fragments into LDS: frag f = kt*8+ct at [f][lane][16B]; 2 per wave
  #pragma unroll
  for (int i = 0; i < 2; ++i) {
    const int f = wave + i * 8, kt = f >> 3, ct = f & 7;
    bf16x8 fr;
    #pragma unroll
    for (int e = 0; e < 8; ++e)
      fr[e] = (__bf16)W1[(kt * 32 + lgrp * 8 + e) * HD + ct * 16 + l16];
    *(bf16x8*)(&ldsW[f * 1024 + lane * 16]) = fr;
  }
  if (threadIdx.x < HD) ldsB[threadIdx.x] = b1[threadIdx.x];
  __syncthreads();

  float seg_acc[8] = {0.f, 0.f, 0.f, 0.f, 0.f, 0.f, 0.f, 0.f};
  const int tiles = (rows + 15) >> 4;
  const float* xb0 = x + (size_t)r0 * ND;

  for (int t = wave; t < tiles; t += 8) {
    // tile load (fragment layout): 4 x dwordx4, 16 rows x 32B per instr
    const int rr = min(t * 16 + l16, rows - 1);
    const float* p = xb0 + (size_t)rr * ND + lgrp * 8;
    f32x4 v0 = *(const f32x4*)(p);
    f32x4 v1 = *(const f32x4*)(p + 4);
    f32x4 v2 = *(const f32x4*)(p + 32);
    f32x4 v3 = *(const f32x4*)(p + 36);
    bf16x8 a0, a1;
    #pragma unroll
    for (int e = 0; e < 4; ++e) {
      a0[e] = (__bf16)v0[e]; a0[e + 4] = (__bf16)v1[e];
      a1[e] = (__bf16)v2[e]; a1[e + 4] = (__bf16)v3[e];
    }
    int lb = lane * 16;
    asm volatile("" : "+v"(lb));    // defeat LICM: frag reads stay in-loop
    const int lim = rows - t * 16;  // >=16 for all but the last tile

    if (lim >= 16) {
      #pragma unroll
      for (int ct = 0; ct < 8; ++ct) {
        const float bias = ldsB[ct * 16 + l16];
        f32x4 c; c[0] = c[1] = c[2] = c[3] = bias;
        bf16x8 f0 = *(const bf16x8*)(&ldsW[ct * 1024 + lb]);
        bf16x8 f1 = *(const bf16x8*)(&ldsW[(8 + ct) * 1024 + lb]);
        c = __builtin_amdgcn_mfma_f32_16x16x32_bf16(a0, f0, c, 0, 0, 0);
        c = __builtin_amdgcn_mfma_f32_16x16x32_bf16(a1, f1, c, 0, 0, 0);
        seg_acc[ct] += (fmaxf(c[0], 0.f) + fmaxf(c[1], 0.f)) +
                       (fmaxf(c[2], 0.f) + fmaxf(c[3], 0.f));
      }
    } else {
      #pragma unroll
      for (int ct = 0; ct < 8; ++ct) {
        const float bias = ldsB[ct * 16 + l16];
        f32x4 c; c[0] = c[1] = c[2] = c[3] = bias;
        bf16x8 f0 = *(const bf16x8*)(&ldsW[ct * 1024 + lb]);
        bf16x8 f1 = *(const bf16x8*)(&ldsW[(8 + ct) * 1024 + lb]);
        c = __builtin_amdgcn_mfma_f32_16x16x32_bf16(a0, f0, c, 0, 0, 0);
        c = __builtin_amdgcn_mfma_f32_16x16x32_bf16(a1, f1, c, 0, 0, 0);
        #pragma unroll
        for (int i = 0; i < 4; ++i)
          seg_acc[ct] += (4 * lgrp + i < lim) ? fmaxf(c[i], 0.f) : 0.f;
      }
    }
  }

  // cross-rowgroup then cross-wave reduce; single plain store (no atomics)
  #pragma unroll
  for (int ct = 0; ct < 8; ++ct) {
    float v = seg_acc[ct];
    v += __shfl_xor(v, 16);
    v += __shfl_xor(v, 32);
    if (lane < 16) ldsR[wave * HD + ct * 16 + l16] = v;
  }
  __syncthreads();
  if (threadIdx.x < HD) {
    float r = 0.f;
    #pragma unroll
    for (int w = 0; w < 8; ++w) r += ldsR[w * HD + threadIdx.x];
    sums[s * HD + threadIdx.x] = r;
  }
}

// K2: per segment: mean -> @W2+b2 (deferred past the mean) -> relu(@W3+b3) -> @W4+b4
__global__ __launch_bounds__(128) void k_rho(const float* __restrict__ sums,
                                             const int* __restrict__ ss,
                                             const float* __restrict__ W2, const float* __restrict__ b2,
                                             const float* __restrict__ W3, const float* __restrict__ b3,
                                             const float* __restrict__ W4, const float* __restrict__ b4,
                                             float* __restrict__ out) {
  const int s = blockIdx.x;
  const int j = threadIdx.x;
  __shared__ float bufA[HD];
  __shared__ float bufB[HD];

  const float c = (float)(ss[s + 1] - ss[s]);
  const float inv = 1.f / fmaxf(c, 1.f);
  bufA[j] = sums[s * HD + j] * inv;
  __syncthreads();

  float hid = b2[j];
  #pragma unroll 4
  for (int k = 0; k < HD; ++k) hid = fmaf(bufA[k], W2[k * HD + j], hid);
  if (c == 0.f) hid = 0.f;                    // reference: empty segment -> hid = 0
  bufB[j] = hid;
  __syncthreads();

  float t = b3[j];
  #pragma unroll 4
  for (int k = 0; k < HD; ++k) t = fmaf(bufB[k], W3[k * HD + j], t);
  t = fmaxf(t, 0.f);
  bufA[j] = t;
  __syncthreads();

  if (j < 16) {
    float o = b4[j];
    #pragma unroll 4
    for (int k = 0; k < HD; ++k) o = fmaf(bufA[k], W4[k * 16 + j], o);
    out[s * 16 + j] = o;
  }
}

extern "C" void kernel_launch(void* const* d_in, const int* in_sizes, int n_in,
                              void* d_out, int out_size, void* d_ws, size_t ws_size,
                              hipStream_t stream) {
  const float* x  = (const float*)d_in[0];
  const int*   xb = (const int*)  d_in[1];
  const float* W1 = (const float*)d_in[2];
  const float* b1 = (const float*)d_in[3];
  const float* W2 = (const float*)d_in[4];
  const float* b2 = (const float*)d_in[5];
  const float* W3 = (const float*)d_in[6];
  const float* b3 = (const float*)d_in[7];
  const float* W4 = (const float*)d_in[8];
  const float* b4 = (const float*)d_in[9];
  float* out = (float*)d_out;
  const int n = in_sizes[1];

  float* sums = (float*)d_ws;                      // [NSEG][HD]
  int*   ss   = (int*)(sums + (size_t)NSEG * HD);  // [NSEG+1]

  k_bounds<<<(NSEG + 1 + 127) / 128, 128, 0, stream>>>(xb, n, ss);
  k_phi<<<NSEG, 512, 0, stream>>>(x, ss, W1, b1, sums);
  k_rho<<<NSEG, 128, 0, stream>>>(sums, ss, W2, b2, W3, b3, W4, b4, out);
}